// Round 1
// baseline (97.079 us; speedup 1.0000x reference)
//
#include <hip/hip_runtime.h>
#include <hip/hip_bf16.h>

typedef __bf16 bf16x8 __attribute__((ext_vector_type(8)));
typedef float f32x4 __attribute__((ext_vector_type(4)));

#define HDIM 4096
#define EDIM 64
#define KBLK (HDIM / 32)  // 128 k-blocks of 32

// ---------------------------------------------------------------------------
// Kernel 1: column-normalize sim_matrix and pack into MFMA B-fragment layout.
// B-frag for mfma_f32_16x16x32_bf16: lane l supplies B[k][n] with n = l&15,
// k = kb*32 + 8*(l>>4) + j  (j = 0..7, contiguous 16B per lane).
// Wp element index: ((nt*KBLK + kb)*64 + lane)*8 + j,  nt = e>>4 (n-tile).
// ---------------------------------------------------------------------------
__global__ __launch_bounds__(256) void pack_w_kernel(const float* __restrict__ W,
                                                     __bf16* __restrict__ Wp) {
  int e = blockIdx.x;      // one block per output column e in [0,64)
  int tid = threadIdx.x;
  __shared__ float red[256];
  float s = 0.f;
  for (int h = tid; h < HDIM; h += 256) {
    float v = W[(size_t)h * EDIM + e];
    s = fmaf(v, v, s);
  }
  red[tid] = s;
  __syncthreads();
  for (int off = 128; off > 0; off >>= 1) {
    if (tid < off) red[tid] += red[tid + off];
    __syncthreads();
  }
  float inv = 1.0f / fmaxf(sqrtf(red[0]), 1e-12f);
  int nt = e >> 4, col = e & 15;
  for (int k = tid; k < HDIM; k += 256) {
    int kb = k >> 5;
    int g = (k >> 3) & 3;
    int j = k & 7;
    float v = W[(size_t)k * EDIM + e] * inv;
    Wp[(size_t)(((nt * KBLK + kb) * 64) + (col + 16 * g)) * 8 + j] = (__bf16)v;
  }
}

// ---------------------------------------------------------------------------
// Kernel 2: fused  norm_h @ Wp  + sigmoid/gate epilogue.
// 4 waves/block, each wave: 16 rows x 64 cols, full K.
// A-frag: lane l holds h[row0 + (l&15)][kb*32 + 8*(l>>4) + j]  (fp32->bf16).
// Row ssq accumulated in fp32 alongside; norm applied after MFMA loop.
// C/D layout (m89-verified): lane l, reg r -> row (l>>4)*4+r, col l&15.
// ---------------------------------------------------------------------------
__global__ __launch_bounds__(256) void gate_main_kernel(
    const float* __restrict__ H, const __bf16* __restrict__ Wp,
    const float* __restrict__ G, float* __restrict__ out, size_t third) {
  const int lane = threadIdx.x & 63;
  const int wave = threadIdx.x >> 6;
  const int m = lane & 15;
  const int g = lane >> 4;
  const int row0 = blockIdx.x * 64 + wave * 16;

  const float* hp = H + (size_t)(row0 + m) * HDIM + g * 8;
  const bf16x8* bbase = reinterpret_cast<const bf16x8*>(Wp) + lane;

  f32x4 acc[4] = {};
  float ssq = 0.f;

#pragma unroll 4
  for (int kb = 0; kb < KBLK; ++kb) {
    float4 a0 = *reinterpret_cast<const float4*>(hp + (size_t)kb * 32);
    float4 a1 = *reinterpret_cast<const float4*>(hp + (size_t)kb * 32 + 4);

    bf16x8 bfr[4];
#pragma unroll
    for (int nt = 0; nt < 4; ++nt) bfr[nt] = bbase[(size_t)(nt * KBLK + kb) * 64];

    bf16x8 af;
    af[0] = (__bf16)a0.x; af[1] = (__bf16)a0.y;
    af[2] = (__bf16)a0.z; af[3] = (__bf16)a0.w;
    af[4] = (__bf16)a1.x; af[5] = (__bf16)a1.y;
    af[6] = (__bf16)a1.z; af[7] = (__bf16)a1.w;

    ssq = fmaf(a0.x, a0.x, ssq); ssq = fmaf(a0.y, a0.y, ssq);
    ssq = fmaf(a0.z, a0.z, ssq); ssq = fmaf(a0.w, a0.w, ssq);
    ssq = fmaf(a1.x, a1.x, ssq); ssq = fmaf(a1.y, a1.y, ssq);
    ssq = fmaf(a1.z, a1.z, ssq); ssq = fmaf(a1.w, a1.w, ssq);

#pragma unroll
    for (int nt = 0; nt < 4; ++nt)
      acc[nt] = __builtin_amdgcn_mfma_f32_16x16x32_bf16(af, bfr[nt], acc[nt], 0, 0, 0);
  }

  // reduce ssq across the 4 lane-groups holding the same row (xor 16, 32)
  ssq += __shfl_xor(ssq, 16, 64);
  ssq += __shfl_xor(ssq, 32, 64);
  float inv = 1.0f / fmaxf(sqrtf(ssq), 1e-12f);

  // lane l needs inv for rows (l>>4)*4 + r; lane t in [0,16) holds row t
  float invr[4];
#pragma unroll
  for (int r = 0; r < 4; ++r) invr[r] = __shfl(inv, g * 4 + r, 64);

#pragma unroll
  for (int nt = 0; nt < 4; ++nt) {
    int e = nt * 16 + m;
    float sg = 1.0f / (1.0f + __expf(-G[e]));
#pragma unroll
    for (int r = 0; r < 4; ++r) {
      size_t idx = (size_t)(row0 + g * 4 + r) * EDIM + e;
      float raw = acc[nt][r] * invr[r];
      float sig = 1.0f / (1.0f + __expf(-raw));
      out[idx] = raw;
      out[idx + third] = sig;
      out[idx + 2 * third] = fmaxf(sig - sg, 0.0f);
    }
  }
}

extern "C" void kernel_launch(void* const* d_in, const int* in_sizes, int n_in,
                              void* d_out, int out_size, void* d_ws, size_t ws_size,
                              hipStream_t stream) {
  const float* H = (const float*)d_in[0];   // [B*S, 4096]
  const float* W = (const float*)d_in[1];   // [4096, 64]
  const float* G = (const float*)d_in[2];   // [64]
  float* out = (float*)d_out;               // 3 x [B*S, 64] concatenated
  __bf16* Wp = (__bf16*)d_ws;               // 512 KB packed normalized W

  int rows = in_sizes[0] / HDIM;            // 16384
  size_t third = (size_t)out_size / 3;      // 1048576

  pack_w_kernel<<<EDIM, 256, 0, stream>>>(W, Wp);
  gate_main_kernel<<<rows / 64, 256, 0, stream>>>(H, Wp, G, out, third);
}

// Round 2
// 85.109 us; speedup vs baseline: 1.1406x; 1.1406x over previous
//
#include <hip/hip_runtime.h>
#include <hip/hip_bf16.h>

typedef __bf16 bf16x8 __attribute__((ext_vector_type(8)));
typedef float f32x4 __attribute__((ext_vector_type(4)));

#define HDIM 4096
#define EDIM 64
#define KBLK (HDIM / 32)   // 128 k-blocks of 32
#define KSPLIT 4
#define KBW (KBLK / KSPLIT) // 32 k-blocks per wave

// ---------------------------------------------------------------------------
// Kernel 1: column-normalize sim_matrix and pack into MFMA B-fragment layout.
// B-frag for mfma_f32_16x16x32_bf16: lane l supplies B[k][n] with n = l&15,
// k = kb*32 + 8*(l>>4) + j  (j = 0..7, contiguous 16B per lane).
// Wp element index: ((nt*KBLK + kb)*64 + lane)*8 + j,  nt = e>>4 (n-tile).
// ---------------------------------------------------------------------------
__global__ __launch_bounds__(256) void pack_w_kernel(const float* __restrict__ W,
                                                     __bf16* __restrict__ Wp) {
  int e = blockIdx.x;      // one block per output column e in [0,64)
  int tid = threadIdx.x;
  __shared__ float red[256];
  float s = 0.f;
  for (int h = tid; h < HDIM; h += 256) {
    float v = W[(size_t)h * EDIM + e];
    s = fmaf(v, v, s);
  }
  red[tid] = s;
  __syncthreads();
  for (int off = 128; off > 0; off >>= 1) {
    if (tid < off) red[tid] += red[tid + off];
    __syncthreads();
  }
  float inv = 1.0f / fmaxf(sqrtf(red[0]), 1e-12f);
  int nt = e >> 4, col = e & 15;
  for (int k = tid; k < HDIM; k += 256) {
    int kb = k >> 5;
    int g = (k >> 3) & 3;
    int j = k & 7;
    float v = W[(size_t)k * EDIM + e] * inv;
    Wp[(size_t)(((nt * KBLK + kb) * 64) + (col + 16 * g)) * 8 + j] = (__bf16)v;
  }
}

// ---------------------------------------------------------------------------
// Kernel 2: fused  norm_h @ Wp  + sigmoid/gate epilogue.
// K-split x4 inside the block: all 4 waves compute the SAME 16 rows, each
// over K/4 = 1024. Partial acc + ssq combined through LDS; wave w then runs
// the epilogue for its own 16-column slice (nt = w).
// Grid: rows/16 = 1024 blocks -> 16 waves/CU (4/SIMD) for latency hiding.
// A-frag: lane l holds h[row0 + (l&15)][kb*32 + 8*(l>>4) + j]  (fp32->bf16).
// C/D layout (m89-verified): lane l, reg r -> row (l>>4)*4+r, col l&15.
// ---------------------------------------------------------------------------
__global__ __launch_bounds__(256, 4) void gate_main_kernel(
    const float* __restrict__ H, const __bf16* __restrict__ Wp,
    const float* __restrict__ G, float* __restrict__ out, size_t third) {
  const int lane = threadIdx.x & 63;
  const int w = threadIdx.x >> 6;       // wave id = K-slice id
  const int m = lane & 15;
  const int g = lane >> 4;
  const int row0 = blockIdx.x * 16;

  // [frag 0..15][wave][lane] -> consecutive lanes hit consecutive banks
  __shared__ float lds_acc[16][KSPLIT][64];
  __shared__ float lds_ssq[KSPLIT][16];

  const int kb0 = w * KBW;
  const float* hp = H + (size_t)(row0 + m) * HDIM + g * 8;
  const bf16x8* bbase = reinterpret_cast<const bf16x8*>(Wp) + lane;

  f32x4 acc[4] = {};
  float ssq0 = 0.f, ssq1 = 0.f;

#pragma unroll 4
  for (int i = 0; i < KBW; ++i) {
    const int kb = kb0 + i;
    float4 a0 = *reinterpret_cast<const float4*>(hp + (size_t)kb * 32);
    float4 a1 = *reinterpret_cast<const float4*>(hp + (size_t)kb * 32 + 4);

    bf16x8 bfr[4];
#pragma unroll
    for (int nt = 0; nt < 4; ++nt) bfr[nt] = bbase[(size_t)(nt * KBLK + kb) * 64];

    bf16x8 af;
    af[0] = (__bf16)a0.x; af[1] = (__bf16)a0.y;
    af[2] = (__bf16)a0.z; af[3] = (__bf16)a0.w;
    af[4] = (__bf16)a1.x; af[5] = (__bf16)a1.y;
    af[6] = (__bf16)a1.z; af[7] = (__bf16)a1.w;

    ssq0 = fmaf(a0.x, a0.x, ssq0); ssq1 = fmaf(a0.y, a0.y, ssq1);
    ssq0 = fmaf(a0.z, a0.z, ssq0); ssq1 = fmaf(a0.w, a0.w, ssq1);
    ssq0 = fmaf(a1.x, a1.x, ssq0); ssq1 = fmaf(a1.y, a1.y, ssq1);
    ssq0 = fmaf(a1.z, a1.z, ssq0); ssq1 = fmaf(a1.w, a1.w, ssq1);

#pragma unroll
    for (int nt = 0; nt < 4; ++nt)
      acc[nt] = __builtin_amdgcn_mfma_f32_16x16x32_bf16(af, bfr[nt], acc[nt], 0, 0, 0);
  }

  // per-row partial ssq for this K-slice: sum lanes {m, m+16, m+32, m+48}
  float ssq = ssq0 + ssq1;
  ssq += __shfl_xor(ssq, 16, 64);
  ssq += __shfl_xor(ssq, 32, 64);

#pragma unroll
  for (int nt = 0; nt < 4; ++nt)
#pragma unroll
    for (int r = 0; r < 4; ++r) lds_acc[nt * 4 + r][w][lane] = acc[nt][r];
  if (g == 0) lds_ssq[w][m] = ssq;
  __syncthreads();

  // epilogue: wave w owns columns [w*16, w*16+16)
  {
    const int e = w * 16 + m;
    const float sg = 1.0f / (1.0f + __expf(-G[e]));
#pragma unroll
    for (int r = 0; r < 4; ++r) {
      const int rowi = g * 4 + r;
      float st = lds_ssq[0][rowi] + lds_ssq[1][rowi] +
                 lds_ssq[2][rowi] + lds_ssq[3][rowi];
      float inv = 1.0f / fmaxf(sqrtf(st), 1e-12f);
      float a = lds_acc[w * 4 + r][0][lane] + lds_acc[w * 4 + r][1][lane] +
                lds_acc[w * 4 + r][2][lane] + lds_acc[w * 4 + r][3][lane];
      float raw = a * inv;
      float sig = 1.0f / (1.0f + __expf(-raw));
      size_t idx = (size_t)(row0 + rowi) * EDIM + e;
      out[idx] = raw;
      out[idx + third] = sig;
      out[idx + 2 * third] = fmaxf(sig - sg, 0.0f);
    }
  }
}

extern "C" void kernel_launch(void* const* d_in, const int* in_sizes, int n_in,
                              void* d_out, int out_size, void* d_ws, size_t ws_size,
                              hipStream_t stream) {
  const float* H = (const float*)d_in[0];   // [B*S, 4096]
  const float* W = (const float*)d_in[1];   // [4096, 64]
  const float* G = (const float*)d_in[2];   // [64]
  float* out = (float*)d_out;               // 3 x [B*S, 64] concatenated
  __bf16* Wp = (__bf16*)d_ws;               // 512 KB packed normalized W

  int rows = in_sizes[0] / HDIM;            // 16384
  size_t third = (size_t)out_size / 3;      // 1048576

  pack_w_kernel<<<EDIM, 256, 0, stream>>>(W, Wp);
  gate_main_kernel<<<rows / 16, 256, 0, stream>>>(H, Wp, G, out, third);
}